// Round 16
// baseline (376.874 us; speedup 1.0000x reference)
//
#include <hip/hip_runtime.h>

typedef unsigned short u16;
typedef float f32x4 __attribute__((ext_vector_type(4)));
typedef float f32x16 __attribute__((ext_vector_type(16)));
typedef short bf16x8 __attribute__((ext_vector_type(8)));
typedef int i32x2 __attribute__((ext_vector_type(2)));

__device__ __forceinline__ u16 f2bf(float f){
  union { float f; unsigned u; } x; x.f = f;
  unsigned r = (x.u + 0x7FFFu + ((x.u >> 16) & 1u)) >> 16;
  return (u16)r;
}

// packed bf16 convert: dst.lo = bf16(lo), dst.hi = bf16(hi)  [verified round 4]
__device__ __forceinline__ unsigned cvtpk(float lo, float hi){
  unsigned r;
  asm("v_cvt_pk_bf16_f32 %0, %1, %2" : "=v"(r) : "v"(lo), "v"(hi));
  return r;
}

// 4x guarded raw v_exp_f32 (D = 2^S0). TRANS->TRANS back-to-back needs no
// wait state; one s_nop 1 closes the TRANS->VALU hazard for the tail def.
__device__ __forceinline__ void exp4q(float& a, float& b, float& c, float& d){
  asm("v_exp_f32 %0, %0\n\t"
      "v_exp_f32 %1, %1\n\t"
      "v_exp_f32 %2, %2\n\t"
      "v_exp_f32 %3, %3\n\t"
      "s_nop 1"
      : "+v"(a), "+v"(b), "+v"(c), "+v"(d));
}

__device__ __forceinline__ f32x4 mfma_bf16(bf16x8 a, bf16x8 b, f32x4 c){
  return __builtin_amdgcn_mfma_f32_16x16x32_bf16(a, b, c, 0, 0, 0);
}

__device__ __forceinline__ f32x16 mfma32(bf16x8 a, bf16x8 b, f32x16 c){
  return __builtin_amdgcn_mfma_f32_32x32x16_bf16(a, b, c, 0, 0, 0);
}

__device__ __forceinline__ void gload16(const u16* g, u16* l){
  __builtin_amdgcn_global_load_lds((__attribute__((address_space(1))) void*)g,
                                   (__attribute__((address_space(3))) void*)l, 16, 0, 0);
}

// ---------------- fused fp32 -> bf16 converts (x, qkv_w, o_w in one launch) ----
__global__ void cvt_all(const float* __restrict__ x, const float* __restrict__ w1,
                        const float* __restrict__ w2,
                        u16* __restrict__ ox, u16* __restrict__ o1, u16* __restrict__ o2,
                        int nx4, int n14, int n24){
  int stride = gridDim.x * blockDim.x;
  int ntot = nx4 + n14 + n24;
  for (int i = blockIdx.x*blockDim.x + threadIdx.x; i < ntot; i += stride){
    const float* src; u16* dst; int j = i;
    if (j < nx4){ src = x; dst = ox; }
    else if (j < nx4 + n14){ j -= nx4; src = w1; dst = o1; }
    else { j -= nx4 + n14; src = w2; dst = o2; }
    float4 v = ((const float4*)src)[j];
    ushort4 o;
    o.x = f2bf(v.x); o.y = f2bf(v.y); o.z = f2bf(v.z); o.w = f2bf(v.w);
    ((ushort4*)dst)[j] = o;
  }
}

// Generic 16B-chunk stager for [rows][32] bf16 tiles (4 slots/row, slot ^= row&3).
template<int NCH, int NTHR>
__device__ __forceinline__ void stage32(const u16* src, int ld, u16* lds, int tid){
#pragma unroll
  for (int i = 0; i < NCH/NTHR; i++){
    int c = i*NTHR + tid;
    int row = c >> 2, slot = c & 3;
    int col = ((slot ^ (row & 3)) << 3);
    gload16(src + (size_t)row*ld + col, lds + ((size_t)(c & ~63) << 3));
  }
}

// ---------- o-proj GEMM (proven 128x128 2-phase path) ----------
__launch_bounds__(256)
__global__ void gemm_bt1(const u16* __restrict__ A, const u16* __restrict__ Bw,
                         const float* __restrict__ bias, float* __restrict__ Co,
                         int M, int Nf, int K)
{
  __shared__ u16 lsA[2][128*32];
  __shared__ u16 lsB[2][128*32];
  int tid = threadIdx.x;
  int wave = tid >> 6, lane = tid & 63, grp = lane >> 4, l16 = lane & 15;
  int ntn = Nf >> 7;
  int bm = blockIdx.x / ntn, bn = blockIdx.x % ntn;
  const u16* Ab = A + (size_t)bm*128*K;
  const u16* Bb = Bw + (size_t)bn*128*K;
  int wm = wave >> 1, wn = wave & 1;
  f32x4 acc[4][4] = {};

  stage32<512,256>(Ab, K, lsA[0], tid);
  stage32<512,256>(Bb, K, lsB[0], tid);
  int nk = K >> 5;
  for (int t = 0; t < nk; t++){
    __syncthreads();
    int cur = t & 1;
    if (t + 1 < nk){
      stage32<512,256>(Ab + ((t+1) << 5), K, lsA[cur^1], tid);
      stage32<512,256>(Bb + ((t+1) << 5), K, lsB[cur^1], tid);
    }
    const u16* la = lsA[cur];
    const u16* lb = lsB[cur];
    bf16x8 af[4], bfr[4];
#pragma unroll
    for (int mf = 0; mf < 4; mf++){
      int row = wm*64 + mf*16 + l16;
      af[mf] = *(const bf16x8*)(la + row*32 + ((grp ^ (row & 3)) << 3));
    }
#pragma unroll
    for (int nf = 0; nf < 4; nf++){
      int row = wn*64 + nf*16 + l16;
      bfr[nf] = *(const bf16x8*)(lb + row*32 + ((grp ^ (row & 3)) << 3));
    }
#pragma unroll
    for (int mf = 0; mf < 4; mf++)
#pragma unroll
      for (int nf = 0; nf < 4; nf++)
        acc[mf][nf] = mfma_bf16(af[mf], bfr[nf], acc[mf][nf]);
  }

  int mrow0 = bm*128 + wm*64;
  int f0 = bn*128 + wn*64;
#pragma unroll
  for (int nf = 0; nf < 4; nf++){
    int f = f0 + nf*16 + l16;
    float bv = bias[f];
#pragma unroll
    for (int mf = 0; mf < 4; mf++){
      int mbase = mrow0 + mf*16 + grp*4;
#pragma unroll
      for (int r = 0; r < 4; r++)
        Co[(size_t)(mbase + r)*Nf + f] = acc[mf][nf][r] + bv;
    }
  }
}

// ---------- QKV GEMM: 256x256 / BK=64 counted-vmcnt pipeline (round 15) ----------
__launch_bounds__(512, 1)
__global__ void gemm_qkv(const u16* __restrict__ A, const u16* __restrict__ Bw,
                         const float* __restrict__ bias,
                         u16* __restrict__ Qp, u16* __restrict__ Kp,
                         u16* __restrict__ Vt, int M, int Nf, int K)
{
  __shared__ u16 lsA[2][256*64];
  __shared__ u16 lsB[2][256*64];
  int tid = threadIdx.x;
  int lane = tid & 63, grp = lane >> 4, l16 = lane & 15;
  int wave = tid >> 6;
  int wr = wave >> 2, wc = wave & 3;          // 2 x 4 wave grid
  int ntn = Nf >> 8;                          // 12
  int bid = (blockIdx.x & 7) * 48 + (blockIdx.x >> 3);
  int bm = bid / ntn, bn = bid % ntn;
  const u16* Ab = A + (size_t)bm*256*K;
  const u16* Bb = Bw + (size_t)bn*256*K;

  f32x4 acc[8][4] = {};

  auto stageHalf = [&](const u16* src, u16* lds, int h){
#pragma unroll
    for (int i = 0; i < 2; i++){
      int c = i*512 + tid;
      int row = h*128 + (c >> 3);
      int col = (((c & 7) ^ (row & 7)) << 3);
      gload16(src + (size_t)row*K + col, lds + h*8192 + ((size_t)(c & ~63) << 3));
    }
  };

  stageHalf(Ab, lsA[0], 0);
  stageHalf(Bb, lsB[0], 0);
  stageHalf(Ab, lsA[0], 1);
  stageHalf(Bb, lsB[0], 1);
  asm volatile("s_waitcnt vmcnt(4)" ::: "memory");

  int nkt = K >> 6;                           // 16
  for (int t = 0; t < nkt; t++){
    const u16* la = lsA[t & 1];
    const u16* lb = lsB[t & 1];
    const u16* As = Ab + ((t+1) << 6);
    const u16* Bs = Bb + ((t+1) << 6);
    u16* dA = lsA[(t+1) & 1];
    u16* dB = lsB[(t+1) & 1];
    bool pf = (t + 1) < nkt;
    bf16x8 af[4][2], bf[2][2];

    // ---- p0 ----
    __builtin_amdgcn_s_barrier();
#pragma unroll
    for (int m = 0; m < 4; m++){
      int grow = (m*2 + wr)*16 + l16;
#pragma unroll
      for (int ks = 0; ks < 2; ks++)
        af[m][ks] = *(const bf16x8*)(la + grow*64 + (((ks*4+grp) ^ (grow & 7)) << 3));
    }
#pragma unroll
    for (int n = 0; n < 2; n++){
      int brow = (n*4 + wc)*16 + l16;
#pragma unroll
      for (int ks = 0; ks < 2; ks++)
        bf[n][ks] = *(const bf16x8*)(lb + brow*64 + (((ks*4+grp) ^ (brow & 7)) << 3));
    }
    if (pf) stageHalf(As, dA, 0);
    __builtin_amdgcn_s_setprio(1);
#pragma unroll
    for (int m = 0; m < 4; m++)
#pragma unroll
      for (int n = 0; n < 2; n++)
#pragma unroll
        for (int ks = 0; ks < 2; ks++)
          acc[m][n] = mfma_bf16(af[m][ks], bf[n][ks], acc[m][n]);
    __builtin_amdgcn_s_setprio(0);
    if (pf) asm volatile("s_waitcnt vmcnt(4)" ::: "memory");
    else    asm volatile("s_waitcnt vmcnt(2)" ::: "memory");

    // ---- p1 ----
    __builtin_amdgcn_s_barrier();
#pragma unroll
    for (int m = 0; m < 4; m++){
      int grow = ((m+4)*2 + wr)*16 + l16;
#pragma unroll
      for (int ks = 0; ks < 2; ks++)
        af[m][ks] = *(const bf16x8*)(la + grow*64 + (((ks*4+grp) ^ (grow & 7)) << 3));
    }
    if (pf) stageHalf(Bs, dB, 0);
    __builtin_amdgcn_s_setprio(1);
#pragma unroll
    for (int m = 0; m < 4; m++)
#pragma unroll
      for (int n = 0; n < 2; n++)
#pragma unroll
        for (int ks = 0; ks < 2; ks++)
          acc[m+4][n] = mfma_bf16(af[m][ks], bf[n][ks], acc[m+4][n]);
    __builtin_amdgcn_s_setprio(0);
    if (pf) asm volatile("s_waitcnt vmcnt(4)" ::: "memory");
    else    asm volatile("s_waitcnt vmcnt(0)" ::: "memory");

    // ---- p2 ----
    __builtin_amdgcn_s_barrier();
#pragma unroll
    for (int n = 0; n < 2; n++){
      int brow = ((n+2)*4 + wc)*16 + l16;
#pragma unroll
      for (int ks = 0; ks < 2; ks++)
        bf[n][ks] = *(const bf16x8*)(lb + brow*64 + (((ks*4+grp) ^ (brow & 7)) << 3));
    }
    if (pf) stageHalf(As, dA, 1);
    __builtin_amdgcn_s_setprio(1);
#pragma unroll
    for (int m = 0; m < 4; m++)
#pragma unroll
      for (int n = 0; n < 2; n++)
#pragma unroll
        for (int ks = 0; ks < 2; ks++)
          acc[m+4][n+2] = mfma_bf16(af[m][ks], bf[n][ks], acc[m+4][n+2]);
    __builtin_amdgcn_s_setprio(0);

    // ---- p3 ----
#pragma unroll
    for (int m = 0; m < 4; m++){
      int grow = (m*2 + wr)*16 + l16;
#pragma unroll
      for (int ks = 0; ks < 2; ks++)
        af[m][ks] = *(const bf16x8*)(la + grow*64 + (((ks*4+grp) ^ (grow & 7)) << 3));
    }
    if (pf) stageHalf(Bs, dB, 1);
    __builtin_amdgcn_s_setprio(1);
#pragma unroll
    for (int m = 0; m < 4; m++)
#pragma unroll
      for (int n = 0; n < 2; n++)
#pragma unroll
        for (int ks = 0; ks < 2; ks++)
          acc[m][n+2] = mfma_bf16(af[m][ks], bf[n][ks], acc[m][n+2]);
    __builtin_amdgcn_s_setprio(0);
    if (pf) asm volatile("s_waitcnt vmcnt(4)" ::: "memory");
  }

  // epilogue: bias + split into Q(scaled)/K/Vt (interleaved rows)
#pragma unroll
  for (int n = 0; n < 4; n++){
    int f = bn*256 + (n*4 + wc)*16 + l16;
    float bv = bias[f];
    int h = f / 192, c = f % 192;             // f = h*3D + c, D=64
#pragma unroll
    for (int m = 0; m < 8; m++){
      int mbase = bm*256 + (m*2 + wr)*16 + grp*4;
      int bb = mbase >> 11, n0 = mbase & 2047;
      size_t bh = (size_t)bb*16 + h;
      if (c >= 128){
        ushort4 w;
        w.x = f2bf(acc[m][n][0] + bv);
        w.y = f2bf(acc[m][n][1] + bv);
        w.z = f2bf(acc[m][n][2] + bv);
        w.w = f2bf(acc[m][n][3] + bv);
        *(ushort4*)(Vt + (bh*64 + (size_t)(c - 128))*2048 + n0) = w;
      } else {
        u16* dst = (c < 64) ? Qp : Kp;
        float sc = (c < 64) ? 0.18033688011f : 1.0f;
        int cc = c & 63;
#pragma unroll
        for (int r = 0; r < 4; r++)
          dst[(bh*2048 + n0 + r)*64 + cc] = f2bf((acc[m][n][r] + bv) * sc);
      }
    }
  }
}

// P-fragment pack: cvt_pk pairs + cross-half permlane32_swap (rounds 7-15).
__device__ __forceinline__ bf16x8 packP(const f32x16& pp, int base){
  unsigned t0 = cvtpk(pp[base+0], pp[base+1]);
  unsigned t1 = cvtpk(pp[base+2], pp[base+3]);
  unsigned t2 = cvtpk(pp[base+4], pp[base+5]);
  unsigned t3 = cvtpk(pp[base+6], pp[base+7]);
  i32x2 r02 = __builtin_amdgcn_permlane32_swap((int)t0, (int)t2, false, false);
  i32x2 r13 = __builtin_amdgcn_permlane32_swap((int)t1, (int)t3, false, false);
  union { unsigned u[4]; bf16x8 v; } pu;
  pu.u[0] = (unsigned)r02.x;
  pu.u[1] = (unsigned)r13.x;
  pu.u[2] = (unsigned)r02.y;
  pu.u[3] = (unsigned)r13.y;
  return pu.v;
}

__device__ __forceinline__ void expv16(f32x16& p){
#pragma unroll
  for (int r = 0; r < 16; r += 4){
    float a = p[r], b = p[r+1], c = p[r+2], d = p[r+3];
    exp4q(a, b, c, d);
    p[r] = a; p[r+1] = b; p[r+2] = c; p[r+3] = d;
  }
}

// Flash attention fwd — LDS-FREE variant. K and V fragments are read
// DIRECTLY from global memory (each lane's frag is a contiguous 16B read;
// the 64 lanes of one read touch only 32 distinct 64B lines since hi-halves
// share lines). Each 8KB K/V tile is L1-resident after the first wave; XCD
// swizzle keeps each bh's 512KB K+V inside one XCD's 4MB L2. This deletes
// all staging instructions, all barriers, all waitcnt drains and the entire
// LDS pipe load (was ~41 us/CU of ds_read) — waves are fully independent.
// Addressing = rounds-3..15 verified frag math minus the LDS swizzle.
// Math identical: swapped-QK^T 32x32, P in-register, fixed-ref softmax,
// guarded v_exp, permlane pack.
// Q(scaled),K: [64][2048][64] bf16; Vt: [64][64][2048] bf16.
// Block: 4 waves x 32 q-rows = 128 q-rows; grid 1024.
__launch_bounds__(256)
__global__ void attn_fwd(const u16* __restrict__ Qg, const u16* __restrict__ Kg,
                         const u16* __restrict__ Vtg, u16* __restrict__ Oa)
{
  int tid = threadIdx.x;
  int lane = tid & 63, wave = tid >> 6;
  int q32 = lane & 31, hi = lane >> 5;
  // XCD swizzle: 8 bh per XCD (grid 1024 % 8 == 0)
  int bid = (blockIdx.x & 7) * 128 + (blockIdx.x >> 3);
  int bh = bid >> 4, qt = bid & 15;
  int b = bh >> 4, h = bh & 15;
  int q0 = qt*128 + wave*32;
  const u16* Qb = Qg + ((size_t)bh*2048 + q0)*64;
  const u16* Kb = Kg + (size_t)bh*2048*64;
  const u16* Vb = Vtg + (size_t)bh*64*2048;

  // Q B-frags: lane holds Q[q=lane&31][kd = s*16 + hi*8 + j]
  bf16x8 qf[4];
#pragma unroll
  for (int s = 0; s < 4; s++)
    qf[s] = *(const bf16x8*)(Qb + q32*64 + s*16 + hi*8);

  f32x16 lacc = {};
  f32x16 oacc[2] = {};

  for (int kt = 0; kt < 32; kt++){
    const u16* kbase = Kb + (size_t)kt*64*64;     // 64 key rows x 64 d
    const u16* vbase = Vb + kt*64;                // 64 d rows x keys (ld 2048)

    // S^T = K Q^T : K-frags direct from global.
    // row = key (q32 / 32+q32), col = s*16 + hi*8 (contiguous 16B).
    f32x16 p0 = {}, p1 = {};
    __builtin_amdgcn_s_setprio(1);
#pragma unroll
    for (int s = 0; s < 4; s++){
      bf16x8 k0 = *(const bf16x8*)(kbase + q32*64 + s*16 + hi*8);
      p0 = mfma32(k0, qf[s], p0);
      bf16x8 k1 = *(const bf16x8*)(kbase + (32+q32)*64 + s*16 + hi*8);
      p1 = mfma32(k1, qf[s], p1);
    }
    __builtin_amdgcn_s_setprio(0);

    // P = 2^S (exact softmax identity; |s| <~ 6 in log2 domain)
    expv16(p0); expv16(p1);
#pragma unroll
    for (int r = 0; r < 16; r++) lacc[r] += p0[r];
#pragma unroll
    for (int r = 0; r < 16; r++) lacc[r] += p1[r];

    // O^T += Vt P : V-frags direct from global.
    // row = d (q32 / 32+q32), col = ks*16 + hi*8 within the 64-key window.
#pragma unroll
    for (int ks = 0; ks < 4; ks++){
      bf16x8 pb = packP((ks < 2) ? p0 : p1, (ks & 1) * 8);
      __builtin_amdgcn_s_setprio(1);
      bf16x8 v0 = *(const bf16x8*)(vbase + (size_t)q32*2048 + ks*16 + hi*8);
      oacc[0] = mfma32(v0, pb, oacc[0]);
      bf16x8 v1 = *(const bf16x8*)(vbase + (size_t)(32+q32)*2048 + ks*16 + hi*8);
      oacc[1] = mfma32(v1, pb, oacc[1]);
      __builtin_amdgcn_s_setprio(0);
    }
  }

  // reduce l once: tree over the 16 vector slots, then cross-half shfl
#pragma unroll
  for (int r = 0; r < 8; r++) lacc[r] += lacc[r+8];
#pragma unroll
  for (int r = 0; r < 4; r++) lacc[r] += lacc[r+4];
  float l = (lacc[0] + lacc[1]) + (lacc[2] + lacc[3]);
  l += __shfl_xor(l, 32, 64);
  float inv = 1.0f / l;

  // O^T[d = dblk*32 + crow(r,hi)][q32] -> Oa[b][n][h*64+d]
  size_t obase = ((size_t)b*2048 + q0 + q32)*1024 + h*64;
#pragma unroll
  for (int dblk = 0; dblk < 2; dblk++)
#pragma unroll
    for (int rb = 0; rb < 4; rb++){
      ushort4 w;
      w.x = f2bf(oacc[dblk][rb*4+0] * inv);
      w.y = f2bf(oacc[dblk][rb*4+1] * inv);
      w.z = f2bf(oacc[dblk][rb*4+2] * inv);
      w.w = f2bf(oacc[dblk][rb*4+3] * inv);
      *(ushort4*)(Oa + obase + dblk*32 + rb*8 + hi*4) = w;
    }
}

extern "C" void kernel_launch(void* const* d_in, const int* in_sizes, int n_in,
                              void* d_out, int out_size, void* d_ws, size_t ws_size,
                              hipStream_t stream)
{
  const float* x    = (const float*)d_in[0];
  const float* qkvw = (const float*)d_in[1];
  const float* qkvb = (const float*)d_in[2];
  const float* ow   = (const float*)d_in[3];
  const float* ob   = (const float*)d_in[4];
  float* out = (float*)d_out;

  u16* xb = (u16*)d_ws;                       // 8192*1024 bf16
  u16* wq = xb + (size_t)8192*1024;           // 3072*1024
  u16* wo = wq + (size_t)3072*1024;           // 1024*1024
  u16* Qp = wo + (size_t)1024*1024;           // 64*2048*64 (pre-scaled)
  u16* Kp = Qp + (size_t)64*2048*64;
  u16* Vt = Kp + (size_t)64*2048*64;          // transposed [bh][d][n]
  u16* Oa = Vt + (size_t)64*2048*64;          // 8192*1024

  // fused converts: x (2.09M float4) + qkv_w (0.79M) + o_w (0.26M)
  cvt_all<<<2048, 256, 0, stream>>>(x, qkvw, ow, xb, wq, wo,
                                    (8192*1024)/4, (3072*1024)/4, (1024*1024)/4);

  gemm_qkv<<<32*12, 512, 0, stream>>>(xb, wq, qkvb, Qp, Kp, Vt, 8192, 3072, 1024);
  attn_fwd<<<1024, 256, 0, stream>>>(Qp, Kp, Vt, Oa);
  gemm_bt1<<<64*8, 256, 0, stream>>>(Oa, wo, ob, out, 8192, 1024, 1024);
}

// Round 17
// 190.777 us; speedup vs baseline: 1.9755x; 1.9755x over previous
//
#include <hip/hip_runtime.h>

typedef unsigned short u16;
typedef float f32x4 __attribute__((ext_vector_type(4)));
typedef float f32x16 __attribute__((ext_vector_type(16)));
typedef short bf16x8 __attribute__((ext_vector_type(8)));
typedef int i32x2 __attribute__((ext_vector_type(2)));

__device__ __forceinline__ u16 f2bf(float f){
  union { float f; unsigned u; } x; x.f = f;
  unsigned r = (x.u + 0x7FFFu + ((x.u >> 16) & 1u)) >> 16;
  return (u16)r;
}

// packed bf16 convert: dst.lo = bf16(lo), dst.hi = bf16(hi)  [verified round 4]
__device__ __forceinline__ unsigned cvtpk(float lo, float hi){
  unsigned r;
  asm("v_cvt_pk_bf16_f32 %0, %1, %2" : "=v"(r) : "v"(lo), "v"(hi));
  return r;
}

// 4x guarded raw v_exp_f32 (D = 2^S0). TRANS->TRANS back-to-back needs no
// wait state; one s_nop 1 closes the TRANS->VALU hazard for the tail def.
__device__ __forceinline__ void exp4q(float& a, float& b, float& c, float& d){
  asm("v_exp_f32 %0, %0\n\t"
      "v_exp_f32 %1, %1\n\t"
      "v_exp_f32 %2, %2\n\t"
      "v_exp_f32 %3, %3\n\t"
      "s_nop 1"
      : "+v"(a), "+v"(b), "+v"(c), "+v"(d));
}

__device__ __forceinline__ f32x4 mfma_bf16(bf16x8 a, bf16x8 b, f32x4 c){
  return __builtin_amdgcn_mfma_f32_16x16x32_bf16(a, b, c, 0, 0, 0);
}

__device__ __forceinline__ f32x16 mfma32(bf16x8 a, bf16x8 b, f32x16 c){
  return __builtin_amdgcn_mfma_f32_32x32x16_bf16(a, b, c, 0, 0, 0);
}

__device__ __forceinline__ void gload16(const u16* g, u16* l){
  __builtin_amdgcn_global_load_lds((__attribute__((address_space(1))) void*)g,
                                   (__attribute__((address_space(3))) void*)l, 16, 0, 0);
}

// ---------------- fused fp32 -> bf16 converts (x, qkv_w, o_w in one launch) ----
__global__ void cvt_all(const float* __restrict__ x, const float* __restrict__ w1,
                        const float* __restrict__ w2,
                        u16* __restrict__ ox, u16* __restrict__ o1, u16* __restrict__ o2,
                        int nx4, int n14, int n24){
  int stride = gridDim.x * blockDim.x;
  int ntot = nx4 + n14 + n24;
  for (int i = blockIdx.x*blockDim.x + threadIdx.x; i < ntot; i += stride){
    const float* src; u16* dst; int j = i;
    if (j < nx4){ src = x; dst = ox; }
    else if (j < nx4 + n14){ j -= nx4; src = w1; dst = o1; }
    else { j -= nx4 + n14; src = w2; dst = o2; }
    float4 v = ((const float4*)src)[j];
    ushort4 o;
    o.x = f2bf(v.x); o.y = f2bf(v.y); o.z = f2bf(v.z); o.w = f2bf(v.w);
    ((ushort4*)dst)[j] = o;
  }
}

// Generic 16B-chunk stager for [rows][32] bf16 tiles (4 slots/row, slot ^= row&3).
template<int NCH, int NTHR>
__device__ __forceinline__ void stage32(const u16* src, int ld, u16* lds, int tid){
#pragma unroll
  for (int i = 0; i < NCH/NTHR; i++){
    int c = i*NTHR + tid;
    int row = c >> 2, slot = c & 3;
    int col = ((slot ^ (row & 3)) << 3);
    gload16(src + (size_t)row*ld + col, lds + ((size_t)(c & ~63) << 3));
  }
}

// 64x64 bf16 tile stager (8 slots/row, slot ^= row&7).
template<int NTHR>
__device__ __forceinline__ void stage64(const u16* src, int ld, u16* lds, int tid){
#pragma unroll
  for (int i = 0; i < 512/NTHR; i++){
    int c = i*NTHR + tid;
    int row = c >> 3, slot = c & 7;
    int col = ((slot ^ (row & 7)) << 3);
    gload16(src + (size_t)row*ld + col, lds + ((size_t)(c & ~63) << 3));
  }
}

// ---------- o-proj GEMM (proven 128x128 2-phase path) ----------
__launch_bounds__(256)
__global__ void gemm_bt1(const u16* __restrict__ A, const u16* __restrict__ Bw,
                         const float* __restrict__ bias, float* __restrict__ Co,
                         int M, int Nf, int K)
{
  __shared__ u16 lsA[2][128*32];
  __shared__ u16 lsB[2][128*32];
  int tid = threadIdx.x;
  int wave = tid >> 6, lane = tid & 63, grp = lane >> 4, l16 = lane & 15;
  int ntn = Nf >> 7;
  int bm = blockIdx.x / ntn, bn = blockIdx.x % ntn;
  const u16* Ab = A + (size_t)bm*128*K;
  const u16* Bb = Bw + (size_t)bn*128*K;
  int wm = wave >> 1, wn = wave & 1;
  f32x4 acc[4][4] = {};

  stage32<512,256>(Ab, K, lsA[0], tid);
  stage32<512,256>(Bb, K, lsB[0], tid);
  int nk = K >> 5;
  for (int t = 0; t < nk; t++){
    __syncthreads();
    int cur = t & 1;
    if (t + 1 < nk){
      stage32<512,256>(Ab + ((t+1) << 5), K, lsA[cur^1], tid);
      stage32<512,256>(Bb + ((t+1) << 5), K, lsB[cur^1], tid);
    }
    const u16* la = lsA[cur];
    const u16* lb = lsB[cur];
    bf16x8 af[4], bfr[4];
#pragma unroll
    for (int mf = 0; mf < 4; mf++){
      int row = wm*64 + mf*16 + l16;
      af[mf] = *(const bf16x8*)(la + row*32 + ((grp ^ (row & 3)) << 3));
    }
#pragma unroll
    for (int nf = 0; nf < 4; nf++){
      int row = wn*64 + nf*16 + l16;
      bfr[nf] = *(const bf16x8*)(lb + row*32 + ((grp ^ (row & 3)) << 3));
    }
#pragma unroll
    for (int mf = 0; mf < 4; mf++)
#pragma unroll
      for (int nf = 0; nf < 4; nf++)
        acc[mf][nf] = mfma_bf16(af[mf], bfr[nf], acc[mf][nf]);
  }

  int mrow0 = bm*128 + wm*64;
  int f0 = bn*128 + wn*64;
#pragma unroll
  for (int nf = 0; nf < 4; nf++){
    int f = f0 + nf*16 + l16;
    float bv = bias[f];
#pragma unroll
    for (int mf = 0; mf < 4; mf++){
      int mbase = mrow0 + mf*16 + grp*4;
#pragma unroll
      for (int r = 0; r < 4; r++)
        Co[(size_t)(mbase + r)*Nf + f] = acc[mf][nf][r] + bv;
    }
  }
}

// ---------- QKV GEMM: 256x256 / BK=64 counted-vmcnt pipeline (round 15) ----------
__launch_bounds__(512, 1)
__global__ void gemm_qkv(const u16* __restrict__ A, const u16* __restrict__ Bw,
                         const float* __restrict__ bias,
                         u16* __restrict__ Qp, u16* __restrict__ Kp,
                         u16* __restrict__ Vt, int M, int Nf, int K)
{
  __shared__ u16 lsA[2][256*64];
  __shared__ u16 lsB[2][256*64];
  int tid = threadIdx.x;
  int lane = tid & 63, grp = lane >> 4, l16 = lane & 15;
  int wave = tid >> 6;
  int wr = wave >> 2, wc = wave & 3;          // 2 x 4 wave grid
  int ntn = Nf >> 8;                          // 12
  int bid = (blockIdx.x & 7) * 48 + (blockIdx.x >> 3);
  int bm = bid / ntn, bn = bid % ntn;
  const u16* Ab = A + (size_t)bm*256*K;
  const u16* Bb = Bw + (size_t)bn*256*K;

  f32x4 acc[8][4] = {};

  auto stageHalf = [&](const u16* src, u16* lds, int h){
#pragma unroll
    for (int i = 0; i < 2; i++){
      int c = i*512 + tid;
      int row = h*128 + (c >> 3);
      int col = (((c & 7) ^ (row & 7)) << 3);
      gload16(src + (size_t)row*K + col, lds + h*8192 + ((size_t)(c & ~63) << 3));
    }
  };

  stageHalf(Ab, lsA[0], 0);
  stageHalf(Bb, lsB[0], 0);
  stageHalf(Ab, lsA[0], 1);
  stageHalf(Bb, lsB[0], 1);
  asm volatile("s_waitcnt vmcnt(4)" ::: "memory");

  int nkt = K >> 6;                           // 16
  for (int t = 0; t < nkt; t++){
    const u16* la = lsA[t & 1];
    const u16* lb = lsB[t & 1];
    const u16* As = Ab + ((t+1) << 6);
    const u16* Bs = Bb + ((t+1) << 6);
    u16* dA = lsA[(t+1) & 1];
    u16* dB = lsB[(t+1) & 1];
    bool pf = (t + 1) < nkt;
    bf16x8 af[4][2], bf[2][2];

    // ---- p0 ----
    __builtin_amdgcn_s_barrier();
#pragma unroll
    for (int m = 0; m < 4; m++){
      int grow = (m*2 + wr)*16 + l16;
#pragma unroll
      for (int ks = 0; ks < 2; ks++)
        af[m][ks] = *(const bf16x8*)(la + grow*64 + (((ks*4+grp) ^ (grow & 7)) << 3));
    }
#pragma unroll
    for (int n = 0; n < 2; n++){
      int brow = (n*4 + wc)*16 + l16;
#pragma unroll
      for (int ks = 0; ks < 2; ks++)
        bf[n][ks] = *(const bf16x8*)(lb + brow*64 + (((ks*4+grp) ^ (brow & 7)) << 3));
    }
    if (pf) stageHalf(As, dA, 0);
    __builtin_amdgcn_s_setprio(1);
#pragma unroll
    for (int m = 0; m < 4; m++)
#pragma unroll
      for (int n = 0; n < 2; n++)
#pragma unroll
        for (int ks = 0; ks < 2; ks++)
          acc[m][n] = mfma_bf16(af[m][ks], bf[n][ks], acc[m][n]);
    __builtin_amdgcn_s_setprio(0);
    if (pf) asm volatile("s_waitcnt vmcnt(4)" ::: "memory");
    else    asm volatile("s_waitcnt vmcnt(2)" ::: "memory");

    // ---- p1 ----
    __builtin_amdgcn_s_barrier();
#pragma unroll
    for (int m = 0; m < 4; m++){
      int grow = ((m+4)*2 + wr)*16 + l16;
#pragma unroll
      for (int ks = 0; ks < 2; ks++)
        af[m][ks] = *(const bf16x8*)(la + grow*64 + (((ks*4+grp) ^ (grow & 7)) << 3));
    }
    if (pf) stageHalf(Bs, dB, 0);
    __builtin_amdgcn_s_setprio(1);
#pragma unroll
    for (int m = 0; m < 4; m++)
#pragma unroll
      for (int n = 0; n < 2; n++)
#pragma unroll
        for (int ks = 0; ks < 2; ks++)
          acc[m+4][n] = mfma_bf16(af[m][ks], bf[n][ks], acc[m+4][n]);
    __builtin_amdgcn_s_setprio(0);
    if (pf) asm volatile("s_waitcnt vmcnt(4)" ::: "memory");
    else    asm volatile("s_waitcnt vmcnt(0)" ::: "memory");

    // ---- p2 ----
    __builtin_amdgcn_s_barrier();
#pragma unroll
    for (int n = 0; n < 2; n++){
      int brow = ((n+2)*4 + wc)*16 + l16;
#pragma unroll
      for (int ks = 0; ks < 2; ks++)
        bf[n][ks] = *(const bf16x8*)(lb + brow*64 + (((ks*4+grp) ^ (brow & 7)) << 3));
    }
    if (pf) stageHalf(As, dA, 1);
    __builtin_amdgcn_s_setprio(1);
#pragma unroll
    for (int m = 0; m < 4; m++)
#pragma unroll
      for (int n = 0; n < 2; n++)
#pragma unroll
        for (int ks = 0; ks < 2; ks++)
          acc[m+4][n+2] = mfma_bf16(af[m][ks], bf[n][ks], acc[m+4][n+2]);
    __builtin_amdgcn_s_setprio(0);

    // ---- p3 ----
#pragma unroll
    for (int m = 0; m < 4; m++){
      int grow = (m*2 + wr)*16 + l16;
#pragma unroll
      for (int ks = 0; ks < 2; ks++)
        af[m][ks] = *(const bf16x8*)(la + grow*64 + (((ks*4+grp) ^ (grow & 7)) << 3));
    }
    if (pf) stageHalf(Bs, dB, 1);
    __builtin_amdgcn_s_setprio(1);
#pragma unroll
    for (int m = 0; m < 4; m++)
#pragma unroll
      for (int n = 0; n < 2; n++)
#pragma unroll
        for (int ks = 0; ks < 2; ks++)
          acc[m][n+2] = mfma_bf16(af[m][ks], bf[n][ks], acc[m][n+2]);
    __builtin_amdgcn_s_setprio(0);
    if (pf) asm volatile("s_waitcnt vmcnt(4)" ::: "memory");
  }

  // epilogue: bias + split into Q(scaled)/K/Vt (interleaved rows)
#pragma unroll
  for (int n = 0; n < 4; n++){
    int f = bn*256 + (n*4 + wc)*16 + l16;
    float bv = bias[f];
    int h = f / 192, c = f % 192;             // f = h*3D + c, D=64
#pragma unroll
    for (int m = 0; m < 8; m++){
      int mbase = bm*256 + (m*2 + wr)*16 + grp*4;
      int bb = mbase >> 11, n0 = mbase & 2047;
      size_t bh = (size_t)bb*16 + h;
      if (c >= 128){
        ushort4 w;
        w.x = f2bf(acc[m][n][0] + bv);
        w.y = f2bf(acc[m][n][1] + bv);
        w.z = f2bf(acc[m][n][2] + bv);
        w.w = f2bf(acc[m][n][3] + bv);
        *(ushort4*)(Vt + (bh*64 + (size_t)(c - 128))*2048 + n0) = w;
      } else {
        u16* dst = (c < 64) ? Qp : Kp;
        float sc = (c < 64) ? 0.18033688011f : 1.0f;
        int cc = c & 63;
#pragma unroll
        for (int r = 0; r < 4; r++)
          dst[(bh*2048 + n0 + r)*64 + cc] = f2bf((acc[m][n][r] + bv) * sc);
      }
    }
  }
}

// P-fragment pack: cvt_pk pairs + cross-half permlane32_swap (rounds 7-15).
__device__ __forceinline__ bf16x8 packP(const f32x16& pp, int base){
  unsigned t0 = cvtpk(pp[base+0], pp[base+1]);
  unsigned t1 = cvtpk(pp[base+2], pp[base+3]);
  unsigned t2 = cvtpk(pp[base+4], pp[base+5]);
  unsigned t3 = cvtpk(pp[base+6], pp[base+7]);
  i32x2 r02 = __builtin_amdgcn_permlane32_swap((int)t0, (int)t2, false, false);
  i32x2 r13 = __builtin_amdgcn_permlane32_swap((int)t1, (int)t3, false, false);
  union { unsigned u[4]; bf16x8 v; } pu;
  pu.u[0] = (unsigned)r02.x;
  pu.u[1] = (unsigned)r13.x;
  pu.u[2] = (unsigned)r02.y;
  pu.u[3] = (unsigned)r13.y;
  return pu.v;
}

__device__ __forceinline__ void expv16(f32x16& p){
#pragma unroll
  for (int r = 0; r < 16; r += 4){
    float a = p[r], b = p[r+1], c = p[r+2], d = p[r+3];
    exp4q(a, b, c, d);
    p[r] = a; p[r+1] = b; p[r+2] = c; p[r+3] = d;
  }
}

// Flash attention fwd (round-15 proven config: 8 waves x 32 q-rows, grid 512,
// 4-buffer counted-vmcnt LDS pipeline, one barrier per tile).
// Round-16's LDS-free variant regressed 3.4x (latency-bound, MfmaUtil 9%):
// LDS staging IS the latency decoupler — loads issue 3 tiles ahead; direct
// global frag reads stall every MFMA on ~200cyc L2 hits. Reverted.
__launch_bounds__(512, 4)
__global__ void attn_fwd(const u16* __restrict__ Qg, const u16* __restrict__ Kg,
                         const u16* __restrict__ Vtg, u16* __restrict__ Oa)
{
  __shared__ u16 kl[4][64*64];
  __shared__ u16 vl[4][64*64];
  int tid = threadIdx.x;
  int lane = tid & 63, wave = tid >> 6;
  int q32 = lane & 31, hi = lane >> 5;
  int bid = (blockIdx.x & 7) * 64 + (blockIdx.x >> 3);
  int bh = bid >> 3, qt = bid & 7;
  int b = bh >> 4, h = bh & 15;
  int q0 = qt*256 + wave*32;
  const u16* Qb = Qg + ((size_t)bh*2048 + q0)*64;
  const u16* Kb = Kg + (size_t)bh*2048*64;
  const u16* Vb = Vtg + (size_t)bh*64*2048;

  bf16x8 qf[4];
#pragma unroll
  for (int s = 0; s < 4; s++)
    qf[s] = *(const bf16x8*)(Qb + q32*64 + s*16 + hi*8);

  f32x16 lacc = {};
  f32x16 oacc[2] = {};

#pragma unroll
  for (int t = 0; t < 3; t++){
    stage64<512>(Kb + (size_t)t*64*64, 64, kl[t], tid);
    stage64<512>(Vb + t*64, 2048, vl[t], tid);
  }

  for (int kt = 0; kt < 32; kt++){
    if (kt < 30)       asm volatile("s_waitcnt vmcnt(4)" ::: "memory");
    else if (kt == 30) asm volatile("s_waitcnt vmcnt(2)" ::: "memory");
    else               asm volatile("s_waitcnt vmcnt(0)" ::: "memory");
    __builtin_amdgcn_s_barrier();
    __builtin_amdgcn_sched_barrier(0);
    if (kt + 3 < 32){
      stage64<512>(Kb + (size_t)(kt+3)*64*64, 64, kl[(kt+3)&3], tid);
      stage64<512>(Vb + (kt+3)*64, 2048, vl[(kt+3)&3], tid);
    }
    const u16* lk = kl[kt & 3];
    const u16* lv = vl[kt & 3];

    f32x16 p0 = {}, p1 = {};
    __builtin_amdgcn_s_setprio(1);
#pragma unroll
    for (int s = 0; s < 4; s++){
      int r0 = q32;
      bf16x8 k0 = *(const bf16x8*)(lk + r0*64 + (((s*2+hi) ^ (r0 & 7)) << 3));
      p0 = mfma32(k0, qf[s], p0);
      int r1 = 32 + q32;
      bf16x8 k1 = *(const bf16x8*)(lk + r1*64 + (((s*2+hi) ^ (r1 & 7)) << 3));
      p1 = mfma32(k1, qf[s], p1);
    }
    __builtin_amdgcn_s_setprio(0);

    expv16(p0); expv16(p1);
#pragma unroll
    for (int r = 0; r < 16; r++) lacc[r] += p0[r];
#pragma unroll
    for (int r = 0; r < 16; r++) lacc[r] += p1[r];

#pragma unroll
    for (int ks = 0; ks < 4; ks++){
      bf16x8 pb = packP((ks < 2) ? p0 : p1, (ks & 1) * 8);
      __builtin_amdgcn_s_setprio(1);
      int rowd0 = q32;
      bf16x8 v0 = *(const bf16x8*)(lv + rowd0*64 + (((ks*2+hi) ^ (rowd0 & 7)) << 3));
      oacc[0] = mfma32(v0, pb, oacc[0]);
      int rowd1 = 32 + q32;
      bf16x8 v1 = *(const bf16x8*)(lv + rowd1*64 + (((ks*2+hi) ^ (rowd1 & 7)) << 3));
      oacc[1] = mfma32(v1, pb, oacc[1]);
      __builtin_amdgcn_s_setprio(0);
    }
  }

#pragma unroll
  for (int r = 0; r < 8; r++) lacc[r] += lacc[r+8];
#pragma unroll
  for (int r = 0; r < 4; r++) lacc[r] += lacc[r+4];
  float l = (lacc[0] + lacc[1]) + (lacc[2] + lacc[3]);
  l += __shfl_xor(l, 32, 64);
  float inv = 1.0f / l;

  size_t obase = ((size_t)b*2048 + q0 + q32)*1024 + h*64;
#pragma unroll
  for (int dblk = 0; dblk < 2; dblk++)
#pragma unroll
    for (int rb = 0; rb < 4; rb++){
      ushort4 w;
      w.x = f2bf(oacc[dblk][rb*4+0] * inv);
      w.y = f2bf(oacc[dblk][rb*4+1] * inv);
      w.z = f2bf(oacc[dblk][rb*4+2] * inv);
      w.w = f2bf(oacc[dblk][rb*4+3] * inv);
      *(ushort4*)(Oa + obase + dblk*32 + rb*8 + hi*4) = w;
    }
}

extern "C" void kernel_launch(void* const* d_in, const int* in_sizes, int n_in,
                              void* d_out, int out_size, void* d_ws, size_t ws_size,
                              hipStream_t stream)
{
  const float* x    = (const float*)d_in[0];
  const float* qkvw = (const float*)d_in[1];
  const float* qkvb = (const float*)d_in[2];
  const float* ow   = (const float*)d_in[3];
  const float* ob   = (const float*)d_in[4];
  float* out = (float*)d_out;

  u16* xb = (u16*)d_ws;                       // 8192*1024 bf16
  u16* wq = xb + (size_t)8192*1024;           // 3072*1024
  u16* wo = wq + (size_t)3072*1024;           // 1024*1024
  u16* Qp = wo + (size_t)1024*1024;           // 64*2048*64 (pre-scaled)
  u16* Kp = Qp + (size_t)64*2048*64;
  u16* Vt = Kp + (size_t)64*2048*64;          // transposed [bh][d][n]
  u16* Oa = Vt + (size_t)64*2048*64;          // 8192*1024

  // fused converts: x (2.09M float4) + qkv_w (0.79M) + o_w (0.26M)
  cvt_all<<<2048, 256, 0, stream>>>(x, qkvw, ow, xb, wq, wo,
                                    (8192*1024)/4, (3072*1024)/4, (1024*1024)/4);

  gemm_qkv<<<32*12, 512, 0, stream>>>(xb, wq, qkvb, Qp, Kp, Vt, 8192, 3072, 1024);
  attn_fwd<<<512, 512, 0, stream>>>(Qp, Kp, Vt, Oa);
  gemm_bt1<<<64*8, 256, 0, stream>>>(Oa, wo, ob, out, 8192, 1024, 1024);
}